// Round 12
// baseline (131.632 us; speedup 1.0000x reference)
//
#include <hip/hip_runtime.h>

// MultiHeadAttention (faithful-to-bug variant), round 11.
// k_attn = round-9 validated form, BYTE-IDENTICAL (every k_attn restructure in
// rounds 5/6/7/10 NaN'd with no mechanism found; frozen). This round widens the
// two m97-family GEMMs (k_qkv, k_out) from 128x64 to the m97-verified 128x128
// tile — constants only, same gl16/linear-LDS/2-barrier structure.
//   Qt[b,n,h,k] = sum_d x[b,n,d] * qp[k,h,d]   (mislabeled-einsum swap)
//   S = Qt·K^T per head ; softmax over n (axis=1 -> COLUMN softmax)
//   O = A·V ; out = O @ op

typedef float f32x4 __attribute__((ext_vector_type(4)));
typedef short s16x4 __attribute__((ext_vector_type(4)));
typedef short s16x8 __attribute__((ext_vector_type(8)));
typedef unsigned short u16;

namespace {
constexpr float C2 = 0.36067376022224085f;  // (1/sqrt(16)) * log2(e)

// workspace byte offsets (16B aligned); total footprint 33.25 MB
constexpr size_t OFF_XB = 0;                                  // xb [4096][1024] bf16
constexpr size_t OFF_WB = OFF_XB + (size_t)4096 * 1024 * 2;   // Wb [1536][1024] bf16
constexpr size_t OFF_WO = OFF_WB + (size_t)1536 * 1024 * 2;   // wo [1024][1024] bf16
constexpr size_t OFF_QT = OFF_WO + (size_t)1024 * 1024 * 2;   // Qt [2][16][2048][16] (pre-scaled)
constexpr size_t OFF_KH = OFF_QT + (size_t)2 * 16 * 2048 * 16 * 2;
constexpr size_t OFF_VT = OFF_KH + (size_t)2 * 16 * 2048 * 16 * 2;  // Vt [2][16][64][2048]
constexpr size_t OFF_ZI = OFF_VT + (size_t)2 * 16 * 64 * 2048 * 2;  // Zi [2][16][2048] f32
constexpr size_t OFF_OH = OFF_ZI + (size_t)2 * 16 * 2048 * 4;       // Oh [2][16][2048][64]
}  // namespace

__device__ __forceinline__ u16 f2bf(float f) {  // RNE f32->bf16
  union { float f; unsigned u; } v; v.f = f;
  return (u16)((v.u + 0x7FFF + ((v.u >> 16) & 1)) >> 16);
}
__device__ __forceinline__ unsigned cvtpk(float lo, float hi) {  // T12 recipe
  unsigned d;
  asm("v_cvt_pk_bf16_f32 %0, %1, %2" : "=v"(d) : "v"(lo), "v"(hi));
  return d;
}
__device__ __forceinline__ float fexp2(float x) {
#if __has_builtin(__builtin_amdgcn_exp2f)
  return __builtin_amdgcn_exp2f(x);
#else
  return exp2f(x);
#endif
}
__device__ __forceinline__ f32x4 mfma16(s16x4 a, s16x4 b, f32x4 c) {
#if __has_builtin(__builtin_amdgcn_mfma_f32_16x16x16_bf16)
  return __builtin_amdgcn_mfma_f32_16x16x16_bf16(a, b, c, 0, 0, 0);
#elif __has_builtin(__builtin_amdgcn_mfma_f32_16x16x16bf16_1k)
  return __builtin_amdgcn_mfma_f32_16x16x16bf16_1k(a, b, c, 0, 0, 0);
#else
  f32x4 d;
  asm volatile("v_mfma_f32_16x16x16_bf16 %0, %1, %2, %3"
               : "=v"(d) : "v"(a), "v"(b), "v"(c));
  return d;
#endif
}
__device__ __forceinline__ void gl16(const void* g, void* l) {  // 16B global->LDS
  __builtin_amdgcn_global_load_lds(
      (const __attribute__((address_space(1))) void*)g,
      (__attribute__((address_space(3))) void*)l, 16, 0, 0);
}

// ---------------------------------------------------------------------------
// k_cvt: f32 -> bf16; packs Wb rows [qp permuted | kp | vp], wo = op.
// ---------------------------------------------------------------------------
__global__ __launch_bounds__(256) void k_cvt(
    const float* __restrict__ x, const float* __restrict__ qp,
    const float* __restrict__ kp, const float* __restrict__ vp,
    const float* __restrict__ op, u16* __restrict__ xb,
    u16* __restrict__ Wb, u16* __restrict__ wo) {
  const int c = blockIdx.x * 256 + threadIdx.x;
  const int XC = (4096 * 1024) / 8, WC = (1536 * 1024) / 8, OC = (1024 * 1024) / 8;
  const float* src; u16* dst;
  if (c < XC) {
    src = x + (size_t)c * 8; dst = xb + (size_t)c * 8;
  } else if (c < XC + WC) {
    const int cc = c - XC;
    const int row = cc >> 7, col = cc & 127;
    if (row < 256) {
      const int h = row >> 4, k = row & 15;
      src = qp + (size_t)(k * 16 + h) * 1024 + col * 8;  // swapped einsum
    } else if (row < 512) {
      src = kp + (size_t)(row - 256) * 1024 + col * 8;
    } else {
      src = vp + (size_t)(row - 512) * 1024 + col * 8;
    }
    dst = Wb + (size_t)cc * 8;
  } else if (c < XC + WC + OC) {
    const int cc = c - XC - WC;
    src = op + (size_t)cc * 8; dst = wo + (size_t)cc * 8;
  } else {
    return;
  }
  float4 lo = *(const float4*)(src);
  float4 hi = *(const float4*)(src + 4);
  union { s16x8 v; unsigned w[4]; } o;
  o.w[0] = cvtpk(lo.x, lo.y); o.w[1] = cvtpk(lo.z, lo.w);
  o.w[2] = cvtpk(hi.x, hi.y); o.w[3] = cvtpk(hi.z, hi.w);
  *(s16x8*)dst = o.v;
}

// ---------------------------------------------------------------------------
// k_qkv: C[4096 x 1536] = xb @ Wb^T. 128x128 tile (m97-verified), BK=64,
// 4 waves (2x2) each owning 64x64; gl16 w16 into LINEAR LDS.
// Epilogue: Qt (scaled by C2) / Kh / Vt (transposed per head).
// ---------------------------------------------------------------------------
__global__ __launch_bounds__(256) void k_qkv(
    const u16* __restrict__ xb, const u16* __restrict__ Wb,
    u16* __restrict__ Qt, u16* __restrict__ Kh, u16* __restrict__ Vt) {
  __shared__ __align__(16) u16 As[128][64];
  __shared__ __align__(16) u16 Bs[128][64];
  const int tid = threadIdx.x;
  const int wave = tid >> 6, lane = tid & 63;
  const int g = lane >> 4, r = lane & 15;
  const int wr = wave >> 1, wc = wave & 1;
  const int r0 = blockIdx.y * 128, c0 = blockIdx.x * 128;
  const int wbase = tid & 192;

  f32x4 acc[4][4];
#pragma unroll
  for (int mi = 0; mi < 4; ++mi)
#pragma unroll
    for (int ni = 0; ni < 4; ++ni)
#pragma unroll
      for (int i = 0; i < 4; ++i) acc[mi][ni][i] = 0.f;

  for (int k0 = 0; k0 < 1024; k0 += 64) {
    __syncthreads();
#pragma unroll
    for (int p = 0; p < 4; ++p) {  // A: 128x64 = 1024 chunks
      const int idx = p * 256 + tid;
      gl16(xb + (size_t)(r0 + (idx >> 3)) * 1024 + k0 + (idx & 7) * 8,
           (char*)As + (size_t)(p * 256 + wbase) * 16);
    }
#pragma unroll
    for (int p = 0; p < 4; ++p) {  // B: 128x64 = 1024 chunks
      const int idx = p * 256 + tid;
      gl16(Wb + (size_t)(c0 + (idx >> 3)) * 1024 + k0 + (idx & 7) * 8,
           (char*)Bs + (size_t)(p * 256 + wbase) * 16);
    }
    __syncthreads();
#pragma unroll
    for (int kf = 0; kf < 2; ++kf) {
      s16x8 a[4], b[4];
#pragma unroll
      for (int mi = 0; mi < 4; ++mi)
        a[mi] = *(const s16x8*)(&As[wr * 64 + mi * 16 + r][kf * 32 + g * 8]);
#pragma unroll
      for (int ni = 0; ni < 4; ++ni)
        b[ni] = *(const s16x8*)(&Bs[wc * 64 + ni * 16 + r][kf * 32 + g * 8]);
#pragma unroll
      for (int mi = 0; mi < 4; ++mi)
#pragma unroll
        for (int ni = 0; ni < 4; ++ni)
          acc[mi][ni] = __builtin_amdgcn_mfma_f32_16x16x32_bf16(a[mi], b[ni], acc[mi][ni], 0, 0, 0);
    }
  }
#pragma unroll
  for (int ni = 0; ni < 4; ++ni) {
    const int c = c0 + wc * 64 + ni * 16 + r;
#pragma unroll
    for (int mi = 0; mi < 4; ++mi) {
      const int rowb = r0 + wr * 64 + mi * 16 + g * 4;
      const int b = rowb >> 11, n = rowb & 2047;
      if (c < 256) {  // Qt, pre-scaled for exp2-direct softmax
        const int h = c >> 4, kk = c & 15;
        u16* p = Qt + (((size_t)b * 16 + h) * 2048 + n) * 16 + kk;
        p[0]  = f2bf(acc[mi][ni][0] * C2);
        p[16] = f2bf(acc[mi][ni][1] * C2);
        p[32] = f2bf(acc[mi][ni][2] * C2);
        p[48] = f2bf(acc[mi][ni][3] * C2);
      } else if (c < 512) {
        const int cc = c - 256;
        const int h = cc >> 4, kk = cc & 15;
        u16* p = Kh + (((size_t)b * 16 + h) * 2048 + n) * 16 + kk;
        p[0]  = f2bf(acc[mi][ni][0]);
        p[16] = f2bf(acc[mi][ni][1]);
        p[32] = f2bf(acc[mi][ni][2]);
        p[48] = f2bf(acc[mi][ni][3]);
      } else {
        const int cc = c - 512;
        const int h = cc >> 6, v = cc & 63;
        ushort4 o;
        o.x = f2bf(acc[mi][ni][0]); o.y = f2bf(acc[mi][ni][1]);
        o.z = f2bf(acc[mi][ni][2]); o.w = f2bf(acc[mi][ni][3]);
        *(ushort4*)(Vt + (((size_t)b * 16 + h) * 64 + v) * 2048 + n) = o;
      }
    }
  }
}

// ---------------------------------------------------------------------------
// k_colsum: Zi[b,h,m] = 1 / sum_n exp2(S'[n,m])  (Qt pre-scaled by C2).
// No in-place mutation of any buffer.
// ---------------------------------------------------------------------------
__global__ __launch_bounds__(256) void k_colsum(
    const u16* __restrict__ Qt, const u16* __restrict__ Kh,
    float* __restrict__ Zi) {
  const int m0 = blockIdx.x * 64;
  const int bh = blockIdx.z * 16 + blockIdx.y;
  const u16* qbase = Qt + (size_t)bh * 2048 * 16;
  const u16* kbase = Kh + (size_t)bh * 2048 * 16;
  __shared__ __align__(16) u16 Ks[64][20];
  __shared__ __align__(16) u16 Qs[128][20];
  __shared__ float Zp[4][64];
  const int tid = threadIdx.x;
  const int wave = tid >> 6, lane = tid & 63;
  const int g = lane >> 4, r = lane & 15;

  {  // stage K tile once
    const int row = tid >> 2, c4 = (tid & 3) * 4;
    *(s16x4*)(&Ks[row][c4]) = *(const s16x4*)(kbase + (size_t)(m0 + row) * 16 + c4);
  }
  __syncthreads();
  s16x4 afr[4];
#pragma unroll
  for (int mf = 0; mf < 4; ++mf) afr[mf] = *(const s16x4*)(&Ks[mf * 16 + r][g * 4]);

  float z[4][4];
#pragma unroll
  for (int mf = 0; mf < 4; ++mf)
#pragma unroll
    for (int i = 0; i < 4; ++i) z[mf][i] = 0.f;

  for (int n0 = 0; n0 < 2048; n0 += 128) {
    __syncthreads();
#pragma unroll
    for (int p = 0; p < 2; ++p) {
      const int ch = p * 256 + tid;
      const int row = ch >> 2, c4 = (ch & 3) * 4;
      *(s16x4*)(&Qs[row][c4]) = *(const s16x4*)(qbase + (size_t)(n0 + row) * 16 + c4);
    }
    __syncthreads();
#pragma unroll
    for (int nf = 0; nf < 2; ++nf) {
      s16x4 bfr = *(const s16x4*)(&Qs[wave * 32 + nf * 16 + r][g * 4]);
#pragma unroll
      for (int mf = 0; mf < 4; ++mf) {
        f32x4 st; st[0] = 0.f; st[1] = 0.f; st[2] = 0.f; st[3] = 0.f;
        st = mfma16(afr[mf], bfr, st);
#pragma unroll
        for (int i = 0; i < 4; ++i) z[mf][i] += fexp2(st[i]);
      }
    }
  }
#pragma unroll
  for (int mf = 0; mf < 4; ++mf)
#pragma unroll
    for (int i = 0; i < 4; ++i) {
      float v = z[mf][i];
      v += __shfl_xor(v, 1); v += __shfl_xor(v, 2);
      v += __shfl_xor(v, 4); v += __shfl_xor(v, 8);
      z[mf][i] = v;
    }
  if (r == 0) {
#pragma unroll
    for (int mf = 0; mf < 4; ++mf)
#pragma unroll
      for (int i = 0; i < 4; ++i) Zp[wave][mf * 16 + g * 4 + i] = z[mf][i];
  }
  __syncthreads();
  if (tid < 64) {
    Zi[(size_t)bh * 2048 + m0 + tid] =
        1.0f / (Zp[0][tid] + Zp[1][tid] + Zp[2][tid] + Zp[3][tid]);
  }
}

// ---------------------------------------------------------------------------
// k_attn: round-9 validated form (BYTE-IDENTICAL). 8 waves / 512 threads;
// waves 0-3 sweep m in [0,1024), waves 4-7 [1024,2048); partial O^T combined
// via comb (union-overlaid on Ks/Vs/Zs). P = exp2(S') * Zi[m] packed bf16.
// ---------------------------------------------------------------------------
__global__ __launch_bounds__(512) void k_attn(
    const u16* __restrict__ Qt, const u16* __restrict__ Kh,
    const u16* __restrict__ Vt, const float* __restrict__ Zi,
    u16* __restrict__ Oh) {
  const int n0 = blockIdx.x * 128;
  const int bh = blockIdx.z * 16 + blockIdx.y;
  const u16* qbase = Qt + (size_t)bh * 2048 * 16;
  const u16* kbase = Kh + (size_t)bh * 2048 * 16;
  const u16* vbase = Vt + (size_t)bh * 64 * 2048;
  const float* zbase = Zi + (size_t)bh * 2048;
  u16* obase = Oh + (size_t)bh * 2048 * 64;

  __shared__ __align__(16) union ShMem {
    struct { u16 Ks[2][64][20]; u16 Vs[2][64][72]; float Zs[2][64]; } s;
    float comb[4][32][68];
  } u;

  const int tid = threadIdx.x;
  const int wave = tid >> 6, lane = tid & 63;
  const int g = lane >> 4, r = lane & 15;
  const int half = wave >> 2, wq = wave & 3;

  s16x4 qfr[2];
#pragma unroll
  for (int nf = 0; nf < 2; ++nf)
    qfr[nf] = *(const s16x4*)(qbase + (size_t)(n0 + wq * 32 + nf * 16 + r) * 16 + g * 4);

  f32x4 oacc[4][2];
#pragma unroll
  for (int vf = 0; vf < 4; ++vf)
#pragma unroll
    for (int nf = 0; nf < 2; ++nf)
#pragma unroll
      for (int i = 0; i < 4; ++i) oacc[vf][nf][i] = 0.f;

  const int ks_hk = tid >> 8, ks_rem = tid & 255;
  const int ks_row = ks_rem >> 2, ks_c4 = (ks_rem & 3) * 4;

  for (int t = 0; t < 16; ++t) {
    __syncthreads();
    // stage K tiles for both halves: 2 x 64 x 16 = 512 s16x4 chunks
    *(s16x4*)(&u.s.Ks[ks_hk][ks_row][ks_c4]) =
        *(const s16x4*)(kbase + (size_t)(ks_hk * 1024 + t * 64 + ks_row) * 16 + ks_c4);
    // stage V tiles for both halves: 2 x 64 x 64 = 1024 s16x8 chunks
#pragma unroll
    for (int p = 0; p < 2; ++p) {
      const int q = p * 512 + tid;
      const int hv = q >> 9, rem = q & 511;
      const int v = rem >> 3, c8 = (rem & 7) * 8;
      *(s16x8*)(&u.s.Vs[hv][v][c8]) =
          *(const s16x8*)(vbase + (size_t)v * 2048 + hv * 1024 + t * 64 + c8);
    }
    // stage Zi for both halves' m-tiles
    if (tid < 128) u.s.Zs[tid >> 6][tid & 63] = zbase[(tid >> 6) * 1024 + t * 64 + (tid & 63)];
    __syncthreads();

    s16x4 kfr[4], va[4][4];
#pragma unroll
    for (int mf = 0; mf < 4; ++mf)
      kfr[mf] = *(const s16x4*)(&u.s.Ks[half][mf * 16 + r][g * 4]);
#pragma unroll
    for (int vf = 0; vf < 4; ++vf)
#pragma unroll
      for (int mf = 0; mf < 4; ++mf)
        va[vf][mf] = *(const s16x4*)(&u.s.Vs[half][vf * 16 + r][mf * 16 + g * 4]);

#pragma unroll
    for (int nf = 0; nf < 2; ++nf) {
      s16x4 pb[4];
#pragma unroll
      for (int mf = 0; mf < 4; ++mf) {
        f32x4 st; st[0] = 0.f; st[1] = 0.f; st[2] = 0.f; st[3] = 0.f;
        st = mfma16(kfr[mf], qfr[nf], st);
        union { s16x4 v4; unsigned w[2]; } pk;
        const int mloc = mf * 16 + g * 4;
        pk.w[0] = cvtpk(fexp2(st[0]) * u.s.Zs[half][mloc + 0],
                        fexp2(st[1]) * u.s.Zs[half][mloc + 1]);
        pk.w[1] = cvtpk(fexp2(st[2]) * u.s.Zs[half][mloc + 2],
                        fexp2(st[3]) * u.s.Zs[half][mloc + 3]);
        pb[mf] = pk.v4;
      }
#pragma unroll
      for (int vf = 0; vf < 4; ++vf)
#pragma unroll
        for (int mf = 0; mf < 4; ++mf)
          oacc[vf][nf] = mfma16(va[vf][mf], pb[mf], oacc[vf][nf]);
    }
  }

  __syncthreads();  // all Ks/Vs/Zs reads done; comb may now overwrite them
  if (half == 1) {
#pragma unroll
    for (int nf = 0; nf < 2; ++nf)
#pragma unroll
      for (int vf = 0; vf < 4; ++vf)
#pragma unroll
        for (int i = 0; i < 4; ++i)
          u.comb[wq][nf * 16 + r][vf * 16 + g * 4 + i] = oacc[vf][nf][i];
  }
  __syncthreads();
  if (half == 0) {
#pragma unroll
    for (int nf = 0; nf < 2; ++nf)
#pragma unroll
      for (int vf = 0; vf < 4; ++vf)
#pragma unroll
        for (int i = 0; i < 4; ++i)
          oacc[vf][nf][i] += u.comb[wq][nf * 16 + r][vf * 16 + g * 4 + i];
#pragma unroll
    for (int nf = 0; nf < 2; ++nf) {
      const int n = n0 + wq * 32 + nf * 16 + r;
#pragma unroll
      for (int vf = 0; vf < 4; ++vf) {
        union { s16x4 v4; unsigned w[2]; } pk;
        pk.w[0] = cvtpk(oacc[vf][nf][0], oacc[vf][nf][1]);
        pk.w[1] = cvtpk(oacc[vf][nf][2], oacc[vf][nf][3]);
        *(s16x4*)(obase + (size_t)n * 64 + vf * 16 + g * 4) = pk.v4;
      }
    }
  }
}

// ---------------------------------------------------------------------------
// k_out: out[4096 x 1024] = Oh(bn x hv) @ wo^T, f32 out. 128x128 tile,
// m97-style gl16 staging (BK=64 == one head, A row-slices contiguous).
// ---------------------------------------------------------------------------
__global__ __launch_bounds__(256) void k_out(
    const u16* __restrict__ Oh, const u16* __restrict__ wo,
    float* __restrict__ out) {
  __shared__ __align__(16) u16 As[128][64];
  __shared__ __align__(16) u16 Bs[128][64];
  const int tid = threadIdx.x;
  const int wave = tid >> 6, lane = tid & 63;
  const int g = lane >> 4, r = lane & 15;
  const int wr = wave >> 1, wc = wave & 1;
  const int r0 = blockIdx.y * 128, c0 = blockIdx.x * 128;
  const int wbase = tid & 192;

  f32x4 acc[4][4];
#pragma unroll
  for (int mi = 0; mi < 4; ++mi)
#pragma unroll
    for (int ni = 0; ni < 4; ++ni)
#pragma unroll
      for (int i = 0; i < 4; ++i) acc[mi][ni][i] = 0.f;

  for (int k0 = 0; k0 < 1024; k0 += 64) {
    const int h = k0 >> 6;
    __syncthreads();
#pragma unroll
    for (int p = 0; p < 4; ++p) {  // A: Oh rows (b,n), k-slice = head h
      const int idx = p * 256 + tid;
      const int row = idx >> 3, c8 = (idx & 7) * 8;
      const int R = r0 + row, b = R >> 11, n = R & 2047;
      gl16(Oh + (((size_t)b * 16 + h) * 2048 + n) * 64 + c8,
           (char*)As + (size_t)(p * 256 + wbase) * 16);
    }
#pragma unroll
    for (int p = 0; p < 4; ++p) {  // B: wo rows d, 128x64
      const int idx = p * 256 + tid;
      gl16(wo + (size_t)(c0 + (idx >> 3)) * 1024 + k0 + (idx & 7) * 8,
           (char*)Bs + (size_t)(p * 256 + wbase) * 16);
    }
    __syncthreads();
#pragma unroll
    for (int kf = 0; kf < 2; ++kf) {
      s16x8 a[4], b[4];
#pragma unroll
      for (int mi = 0; mi < 4; ++mi)
        a[mi] = *(const s16x8*)(&As[wr * 64 + mi * 16 + r][kf * 32 + g * 8]);
#pragma unroll
      for (int ni = 0; ni < 4; ++ni)
        b[ni] = *(const s16x8*)(&Bs[wc * 64 + ni * 16 + r][kf * 32 + g * 8]);
#pragma unroll
      for (int mi = 0; mi < 4; ++mi)
#pragma unroll
        for (int ni = 0; ni < 4; ++ni)
          acc[mi][ni] = __builtin_amdgcn_mfma_f32_16x16x32_bf16(a[mi], b[ni], acc[mi][ni], 0, 0, 0);
    }
  }
#pragma unroll
  for (int ni = 0; ni < 4; ++ni) {
    const int d = c0 + wc * 64 + ni * 16 + r;
#pragma unroll
    for (int mi = 0; mi < 4; ++mi) {
      const int rowb = r0 + wr * 64 + mi * 16 + g * 4;
#pragma unroll
      for (int i = 0; i < 4; ++i)
        out[(size_t)(rowb + i) * 1024 + d] = acc[mi][ni][i];
    }
  }
}

// ---------------------------------------------------------------------------
extern "C" void kernel_launch(void* const* d_in, const int* in_sizes, int n_in,
                              void* d_out, int out_size, void* d_ws, size_t ws_size,
                              hipStream_t stream) {
  (void)in_sizes; (void)n_in; (void)out_size; (void)ws_size;
  const float* x  = (const float*)d_in[0];
  const float* qp = (const float*)d_in[1];
  const float* kp = (const float*)d_in[2];
  const float* vp = (const float*)d_in[3];
  const float* op = (const float*)d_in[4];
  float* out = (float*)d_out;
  char* ws = (char*)d_ws;

  u16* xb = (u16*)(ws + OFF_XB);
  u16* Wb = (u16*)(ws + OFF_WB);
  u16* wo = (u16*)(ws + OFF_WO);
  u16* Qt = (u16*)(ws + OFF_QT);
  u16* Kh = (u16*)(ws + OFF_KH);
  u16* Vt = (u16*)(ws + OFF_VT);
  float* Zi = (float*)(ws + OFF_ZI);
  u16* Oh = (u16*)(ws + OFF_OH);

  k_cvt<<<3328, 256, 0, stream>>>(x, qp, kp, vp, op, xb, Wb, wo);
  k_qkv<<<dim3(12, 32), 256, 0, stream>>>(xb, Wb, Qt, Kh, Vt);
  k_colsum<<<dim3(32, 16, 2), 256, 0, stream>>>(Qt, Kh, Zi);
  k_attn<<<dim3(16, 16, 2), 512, 0, stream>>>(Qt, Kh, Vt, Zi, Oh);
  k_out<<<dim3(8, 32), 256, 0, stream>>>(Oh, wo, out);
}

// Round 13
// 119.703 us; speedup vs baseline: 1.0997x; 1.0997x over previous
//
#include <hip/hip_runtime.h>

// MultiHeadAttention (faithful-to-bug variant), round 12 = EXACT round-9 revert.
// Round 11's 128x128 GEMM tiles regressed (-12 us): grid fell to 1-1.5
// blocks/CU and latency overlap collapsed — at these shapes parallelism beats
// tile reuse. This re-banks the best validated configuration (119.75 us):
// k_qkv/k_out at 128x64 (m97 gl16 staging), k_attn frozen round-9 form
// (8-wave m-split + union-overlaid comb), k_colsum Zi, k_cvt pack.
//   Qt[b,n,h,k] = sum_d x[b,n,d] * qp[k,h,d]   (mislabeled-einsum swap)
//   S = Qt·K^T per head ; softmax over n (axis=1 -> COLUMN softmax)
//   O = A·V ; out = O @ op

typedef float f32x4 __attribute__((ext_vector_type(4)));
typedef short s16x4 __attribute__((ext_vector_type(4)));
typedef short s16x8 __attribute__((ext_vector_type(8)));
typedef unsigned short u16;

namespace {
constexpr float C2 = 0.36067376022224085f;  // (1/sqrt(16)) * log2(e)

// workspace byte offsets (16B aligned); total footprint 33.25 MB
constexpr size_t OFF_XB = 0;                                  // xb [4096][1024] bf16
constexpr size_t OFF_WB = OFF_XB + (size_t)4096 * 1024 * 2;   // Wb [1536][1024] bf16
constexpr size_t OFF_WO = OFF_WB + (size_t)1536 * 1024 * 2;   // wo [1024][1024] bf16
constexpr size_t OFF_QT = OFF_WO + (size_t)1024 * 1024 * 2;   // Qt [2][16][2048][16] (pre-scaled)
constexpr size_t OFF_KH = OFF_QT + (size_t)2 * 16 * 2048 * 16 * 2;
constexpr size_t OFF_VT = OFF_KH + (size_t)2 * 16 * 2048 * 16 * 2;  // Vt [2][16][64][2048]
constexpr size_t OFF_ZI = OFF_VT + (size_t)2 * 16 * 64 * 2048 * 2;  // Zi [2][16][2048] f32
constexpr size_t OFF_OH = OFF_ZI + (size_t)2 * 16 * 2048 * 4;       // Oh [2][16][2048][64]
}  // namespace

__device__ __forceinline__ u16 f2bf(float f) {  // RNE f32->bf16
  union { float f; unsigned u; } v; v.f = f;
  return (u16)((v.u + 0x7FFF + ((v.u >> 16) & 1)) >> 16);
}
__device__ __forceinline__ unsigned cvtpk(float lo, float hi) {  // T12 recipe
  unsigned d;
  asm("v_cvt_pk_bf16_f32 %0, %1, %2" : "=v"(d) : "v"(lo), "v"(hi));
  return d;
}
__device__ __forceinline__ float fexp2(float x) {
#if __has_builtin(__builtin_amdgcn_exp2f)
  return __builtin_amdgcn_exp2f(x);
#else
  return exp2f(x);
#endif
}
__device__ __forceinline__ f32x4 mfma16(s16x4 a, s16x4 b, f32x4 c) {
#if __has_builtin(__builtin_amdgcn_mfma_f32_16x16x16_bf16)
  return __builtin_amdgcn_mfma_f32_16x16x16_bf16(a, b, c, 0, 0, 0);
#elif __has_builtin(__builtin_amdgcn_mfma_f32_16x16x16bf16_1k)
  return __builtin_amdgcn_mfma_f32_16x16x16bf16_1k(a, b, c, 0, 0, 0);
#else
  f32x4 d;
  asm volatile("v_mfma_f32_16x16x16_bf16 %0, %1, %2, %3"
               : "=v"(d) : "v"(a), "v"(b), "v"(c));
  return d;
#endif
}
__device__ __forceinline__ void gl16(const void* g, void* l) {  // 16B global->LDS
  __builtin_amdgcn_global_load_lds(
      (const __attribute__((address_space(1))) void*)g,
      (__attribute__((address_space(3))) void*)l, 16, 0, 0);
}

// ---------------------------------------------------------------------------
// k_cvt: f32 -> bf16; packs Wb rows [qp permuted | kp | vp], wo = op.
// ---------------------------------------------------------------------------
__global__ __launch_bounds__(256) void k_cvt(
    const float* __restrict__ x, const float* __restrict__ qp,
    const float* __restrict__ kp, const float* __restrict__ vp,
    const float* __restrict__ op, u16* __restrict__ xb,
    u16* __restrict__ Wb, u16* __restrict__ wo) {
  const int c = blockIdx.x * 256 + threadIdx.x;
  const int XC = (4096 * 1024) / 8, WC = (1536 * 1024) / 8, OC = (1024 * 1024) / 8;
  const float* src; u16* dst;
  if (c < XC) {
    src = x + (size_t)c * 8; dst = xb + (size_t)c * 8;
  } else if (c < XC + WC) {
    const int cc = c - XC;
    const int row = cc >> 7, col = cc & 127;
    if (row < 256) {
      const int h = row >> 4, k = row & 15;
      src = qp + (size_t)(k * 16 + h) * 1024 + col * 8;  // swapped einsum
    } else if (row < 512) {
      src = kp + (size_t)(row - 256) * 1024 + col * 8;
    } else {
      src = vp + (size_t)(row - 512) * 1024 + col * 8;
    }
    dst = Wb + (size_t)cc * 8;
  } else if (c < XC + WC + OC) {
    const int cc = c - XC - WC;
    src = op + (size_t)cc * 8; dst = wo + (size_t)cc * 8;
  } else {
    return;
  }
  float4 lo = *(const float4*)(src);
  float4 hi = *(const float4*)(src + 4);
  union { s16x8 v; unsigned w[4]; } o;
  o.w[0] = cvtpk(lo.x, lo.y); o.w[1] = cvtpk(lo.z, lo.w);
  o.w[2] = cvtpk(hi.x, hi.y); o.w[3] = cvtpk(hi.z, hi.w);
  *(s16x8*)dst = o.v;
}

// ---------------------------------------------------------------------------
// k_qkv: C[4096 x 1536] = xb @ Wb^T. 128x64 tile, BK=64, 4 waves (2x2),
// global_load_lds w16 into LINEAR LDS (m97 structure).
// Epilogue: Qt (scaled by C2) / Kh / Vt (transposed per head).
// ---------------------------------------------------------------------------
__global__ __launch_bounds__(256) void k_qkv(
    const u16* __restrict__ xb, const u16* __restrict__ Wb,
    u16* __restrict__ Qt, u16* __restrict__ Kh, u16* __restrict__ Vt) {
  __shared__ __align__(16) u16 As[128][64];
  __shared__ __align__(16) u16 Bs[64][64];
  const int tid = threadIdx.x;
  const int wave = tid >> 6, lane = tid & 63;
  const int g = lane >> 4, r = lane & 15;
  const int wr = wave >> 1, wc = wave & 1;
  const int r0 = blockIdx.y * 128, c0 = blockIdx.x * 64;
  const int wbase = tid & 192;

  f32x4 acc[4][2];
#pragma unroll
  for (int mi = 0; mi < 4; ++mi)
#pragma unroll
    for (int ni = 0; ni < 2; ++ni)
#pragma unroll
      for (int i = 0; i < 4; ++i) acc[mi][ni][i] = 0.f;

  for (int k0 = 0; k0 < 1024; k0 += 64) {
    __syncthreads();
#pragma unroll
    for (int p = 0; p < 4; ++p) {  // A: 128x64 = 1024 chunks
      const int idx = p * 256 + tid;
      gl16(xb + (size_t)(r0 + (idx >> 3)) * 1024 + k0 + (idx & 7) * 8,
           (char*)As + (size_t)(p * 256 + wbase) * 16);
    }
#pragma unroll
    for (int p = 0; p < 2; ++p) {  // B: 64x64 = 512 chunks
      const int idx = p * 256 + tid;
      gl16(Wb + (size_t)(c0 + (idx >> 3)) * 1024 + k0 + (idx & 7) * 8,
           (char*)Bs + (size_t)(p * 256 + wbase) * 16);
    }
    __syncthreads();
#pragma unroll
    for (int kf = 0; kf < 2; ++kf) {
      s16x8 a[4], b[2];
#pragma unroll
      for (int mi = 0; mi < 4; ++mi)
        a[mi] = *(const s16x8*)(&As[wr * 64 + mi * 16 + r][kf * 32 + g * 8]);
#pragma unroll
      for (int ni = 0; ni < 2; ++ni)
        b[ni] = *(const s16x8*)(&Bs[wc * 32 + ni * 16 + r][kf * 32 + g * 8]);
#pragma unroll
      for (int mi = 0; mi < 4; ++mi)
#pragma unroll
        for (int ni = 0; ni < 2; ++ni)
          acc[mi][ni] = __builtin_amdgcn_mfma_f32_16x16x32_bf16(a[mi], b[ni], acc[mi][ni], 0, 0, 0);
    }
  }
#pragma unroll
  for (int ni = 0; ni < 2; ++ni) {
    const int c = c0 + wc * 32 + ni * 16 + r;
#pragma unroll
    for (int mi = 0; mi < 4; ++mi) {
      const int rowb = r0 + wr * 64 + mi * 16 + g * 4;
      const int b = rowb >> 11, n = rowb & 2047;
      if (c < 256) {  // Qt, pre-scaled for exp2-direct softmax
        const int h = c >> 4, kk = c & 15;
        u16* p = Qt + (((size_t)b * 16 + h) * 2048 + n) * 16 + kk;
        p[0]  = f2bf(acc[mi][ni][0] * C2);
        p[16] = f2bf(acc[mi][ni][1] * C2);
        p[32] = f2bf(acc[mi][ni][2] * C2);
        p[48] = f2bf(acc[mi][ni][3] * C2);
      } else if (c < 512) {
        const int cc = c - 256;
        const int h = cc >> 4, kk = cc & 15;
        u16* p = Kh + (((size_t)b * 16 + h) * 2048 + n) * 16 + kk;
        p[0]  = f2bf(acc[mi][ni][0]);
        p[16] = f2bf(acc[mi][ni][1]);
        p[32] = f2bf(acc[mi][ni][2]);
        p[48] = f2bf(acc[mi][ni][3]);
      } else {
        const int cc = c - 512;
        const int h = cc >> 6, v = cc & 63;
        ushort4 o;
        o.x = f2bf(acc[mi][ni][0]); o.y = f2bf(acc[mi][ni][1]);
        o.z = f2bf(acc[mi][ni][2]); o.w = f2bf(acc[mi][ni][3]);
        *(ushort4*)(Vt + (((size_t)b * 16 + h) * 64 + v) * 2048 + n) = o;
      }
    }
  }
}

// ---------------------------------------------------------------------------
// k_colsum: Zi[b,h,m] = 1 / sum_n exp2(S'[n,m])  (Qt pre-scaled by C2).
// No in-place mutation of any buffer.
// ---------------------------------------------------------------------------
__global__ __launch_bounds__(256) void k_colsum(
    const u16* __restrict__ Qt, const u16* __restrict__ Kh,
    float* __restrict__ Zi) {
  const int m0 = blockIdx.x * 64;
  const int bh = blockIdx.z * 16 + blockIdx.y;
  const u16* qbase = Qt + (size_t)bh * 2048 * 16;
  const u16* kbase = Kh + (size_t)bh * 2048 * 16;
  __shared__ __align__(16) u16 Ks[64][20];
  __shared__ __align__(16) u16 Qs[128][20];
  __shared__ float Zp[4][64];
  const int tid = threadIdx.x;
  const int wave = tid >> 6, lane = tid & 63;
  const int g = lane >> 4, r = lane & 15;

  {  // stage K tile once
    const int row = tid >> 2, c4 = (tid & 3) * 4;
    *(s16x4*)(&Ks[row][c4]) = *(const s16x4*)(kbase + (size_t)(m0 + row) * 16 + c4);
  }
  __syncthreads();
  s16x4 afr[4];
#pragma unroll
  for (int mf = 0; mf < 4; ++mf) afr[mf] = *(const s16x4*)(&Ks[mf * 16 + r][g * 4]);

  float z[4][4];
#pragma unroll
  for (int mf = 0; mf < 4; ++mf)
#pragma unroll
    for (int i = 0; i < 4; ++i) z[mf][i] = 0.f;

  for (int n0 = 0; n0 < 2048; n0 += 128) {
    __syncthreads();
#pragma unroll
    for (int p = 0; p < 2; ++p) {
      const int ch = p * 256 + tid;
      const int row = ch >> 2, c4 = (ch & 3) * 4;
      *(s16x4*)(&Qs[row][c4]) = *(const s16x4*)(qbase + (size_t)(n0 + row) * 16 + c4);
    }
    __syncthreads();
#pragma unroll
    for (int nf = 0; nf < 2; ++nf) {
      s16x4 bfr = *(const s16x4*)(&Qs[wave * 32 + nf * 16 + r][g * 4]);
#pragma unroll
      for (int mf = 0; mf < 4; ++mf) {
        f32x4 st; st[0] = 0.f; st[1] = 0.f; st[2] = 0.f; st[3] = 0.f;
        st = mfma16(afr[mf], bfr, st);
#pragma unroll
        for (int i = 0; i < 4; ++i) z[mf][i] += fexp2(st[i]);
      }
    }
  }
#pragma unroll
  for (int mf = 0; mf < 4; ++mf)
#pragma unroll
    for (int i = 0; i < 4; ++i) {
      float v = z[mf][i];
      v += __shfl_xor(v, 1); v += __shfl_xor(v, 2);
      v += __shfl_xor(v, 4); v += __shfl_xor(v, 8);
      z[mf][i] = v;
    }
  if (r == 0) {
#pragma unroll
    for (int mf = 0; mf < 4; ++mf)
#pragma unroll
      for (int i = 0; i < 4; ++i) Zp[wave][mf * 16 + g * 4 + i] = z[mf][i];
  }
  __syncthreads();
  if (tid < 64) {
    Zi[(size_t)bh * 2048 + m0 + tid] =
        1.0f / (Zp[0][tid] + Zp[1][tid] + Zp[2][tid] + Zp[3][tid]);
  }
}

// ---------------------------------------------------------------------------
// k_attn: round-9 validated form (BYTE-IDENTICAL, frozen). 8 waves / 512
// threads; waves 0-3 sweep m in [0,1024), waves 4-7 [1024,2048); partial O^T
// combined via comb (union-overlaid on Ks/Vs/Zs). P = exp2(S')*Zi[m] bf16.
// ---------------------------------------------------------------------------
__global__ __launch_bounds__(512) void k_attn(
    const u16* __restrict__ Qt, const u16* __restrict__ Kh,
    const u16* __restrict__ Vt, const float* __restrict__ Zi,
    u16* __restrict__ Oh) {
  const int n0 = blockIdx.x * 128;
  const int bh = blockIdx.z * 16 + blockIdx.y;
  const u16* qbase = Qt + (size_t)bh * 2048 * 16;
  const u16* kbase = Kh + (size_t)bh * 2048 * 16;
  const u16* vbase = Vt + (size_t)bh * 64 * 2048;
  const float* zbase = Zi + (size_t)bh * 2048;
  u16* obase = Oh + (size_t)bh * 2048 * 64;

  __shared__ __align__(16) union ShMem {
    struct { u16 Ks[2][64][20]; u16 Vs[2][64][72]; float Zs[2][64]; } s;
    float comb[4][32][68];
  } u;

  const int tid = threadIdx.x;
  const int wave = tid >> 6, lane = tid & 63;
  const int g = lane >> 4, r = lane & 15;
  const int half = wave >> 2, wq = wave & 3;

  s16x4 qfr[2];
#pragma unroll
  for (int nf = 0; nf < 2; ++nf)
    qfr[nf] = *(const s16x4*)(qbase + (size_t)(n0 + wq * 32 + nf * 16 + r) * 16 + g * 4);

  f32x4 oacc[4][2];
#pragma unroll
  for (int vf = 0; vf < 4; ++vf)
#pragma unroll
    for (int nf = 0; nf < 2; ++nf)
#pragma unroll
      for (int i = 0; i < 4; ++i) oacc[vf][nf][i] = 0.f;

  const int ks_hk = tid >> 8, ks_rem = tid & 255;
  const int ks_row = ks_rem >> 2, ks_c4 = (ks_rem & 3) * 4;

  for (int t = 0; t < 16; ++t) {
    __syncthreads();
    // stage K tiles for both halves: 2 x 64 x 16 = 512 s16x4 chunks
    *(s16x4*)(&u.s.Ks[ks_hk][ks_row][ks_c4]) =
        *(const s16x4*)(kbase + (size_t)(ks_hk * 1024 + t * 64 + ks_row) * 16 + ks_c4);
    // stage V tiles for both halves: 2 x 64 x 64 = 1024 s16x8 chunks
#pragma unroll
    for (int p = 0; p < 2; ++p) {
      const int q = p * 512 + tid;
      const int hv = q >> 9, rem = q & 511;
      const int v = rem >> 3, c8 = (rem & 7) * 8;
      *(s16x8*)(&u.s.Vs[hv][v][c8]) =
          *(const s16x8*)(vbase + (size_t)v * 2048 + hv * 1024 + t * 64 + c8);
    }
    // stage Zi for both halves' m-tiles
    if (tid < 128) u.s.Zs[tid >> 6][tid & 63] = zbase[(tid >> 6) * 1024 + t * 64 + (tid & 63)];
    __syncthreads();

    s16x4 kfr[4], va[4][4];
#pragma unroll
    for (int mf = 0; mf < 4; ++mf)
      kfr[mf] = *(const s16x4*)(&u.s.Ks[half][mf * 16 + r][g * 4]);
#pragma unroll
    for (int vf = 0; vf < 4; ++vf)
#pragma unroll
      for (int mf = 0; mf < 4; ++mf)
        va[vf][mf] = *(const s16x4*)(&u.s.Vs[half][vf * 16 + r][mf * 16 + g * 4]);

#pragma unroll
    for (int nf = 0; nf < 2; ++nf) {
      s16x4 pb[4];
#pragma unroll
      for (int mf = 0; mf < 4; ++mf) {
        f32x4 st; st[0] = 0.f; st[1] = 0.f; st[2] = 0.f; st[3] = 0.f;
        st = mfma16(kfr[mf], qfr[nf], st);
        union { s16x4 v4; unsigned w[2]; } pk;
        const int mloc = mf * 16 + g * 4;
        pk.w[0] = cvtpk(fexp2(st[0]) * u.s.Zs[half][mloc + 0],
                        fexp2(st[1]) * u.s.Zs[half][mloc + 1]);
        pk.w[1] = cvtpk(fexp2(st[2]) * u.s.Zs[half][mloc + 2],
                        fexp2(st[3]) * u.s.Zs[half][mloc + 3]);
        pb[mf] = pk.v4;
      }
#pragma unroll
      for (int vf = 0; vf < 4; ++vf)
#pragma unroll
        for (int mf = 0; mf < 4; ++mf)
          oacc[vf][nf] = mfma16(va[vf][mf], pb[mf], oacc[vf][nf]);
    }
  }

  __syncthreads();  // all Ks/Vs/Zs reads done; comb may now overwrite them
  if (half == 1) {
#pragma unroll
    for (int nf = 0; nf < 2; ++nf)
#pragma unroll
      for (int vf = 0; vf < 4; ++vf)
#pragma unroll
        for (int i = 0; i < 4; ++i)
          u.comb[wq][nf * 16 + r][vf * 16 + g * 4 + i] = oacc[vf][nf][i];
  }
  __syncthreads();
  if (half == 0) {
#pragma unroll
    for (int nf = 0; nf < 2; ++nf)
#pragma unroll
      for (int vf = 0; vf < 4; ++vf)
#pragma unroll
        for (int i = 0; i < 4; ++i)
          oacc[vf][nf][i] += u.comb[wq][nf * 16 + r][vf * 16 + g * 4 + i];
#pragma unroll
    for (int nf = 0; nf < 2; ++nf) {
      const int n = n0 + wq * 32 + nf * 16 + r;
#pragma unroll
      for (int vf = 0; vf < 4; ++vf) {
        union { s16x4 v4; unsigned w[2]; } pk;
        pk.w[0] = cvtpk(oacc[vf][nf][0], oacc[vf][nf][1]);
        pk.w[1] = cvtpk(oacc[vf][nf][2], oacc[vf][nf][3]);
        *(s16x4*)(obase + (size_t)n * 64 + vf * 16 + g * 4) = pk.v4;
      }
    }
  }
}

// ---------------------------------------------------------------------------
// k_out: out[4096 x 1024] = Oh(bn x hv) @ wo^T, f32 out. m97-style staging.
// ---------------------------------------------------------------------------
__global__ __launch_bounds__(256) void k_out(
    const u16* __restrict__ Oh, const u16* __restrict__ wo,
    float* __restrict__ out) {
  __shared__ __align__(16) u16 As[128][64];
  __shared__ __align__(16) u16 Bs[64][64];
  const int tid = threadIdx.x;
  const int wave = tid >> 6, lane = tid & 63;
  const int g = lane >> 4, r = lane & 15;
  const int wr = wave >> 1, wc = wave & 1;
  const int r0 = blockIdx.y * 128, c0 = blockIdx.x * 64;
  const int wbase = tid & 192;

  f32x4 acc[4][2];
#pragma unroll
  for (int mi = 0; mi < 4; ++mi)
#pragma unroll
    for (int ni = 0; ni < 2; ++ni)
#pragma unroll
      for (int i = 0; i < 4; ++i) acc[mi][ni][i] = 0.f;

  for (int k0 = 0; k0 < 1024; k0 += 64) {
    const int h = k0 >> 6;
    __syncthreads();
#pragma unroll
    for (int p = 0; p < 4; ++p) {  // A: Oh rows (b,n), k-slice = head h
      const int idx = p * 256 + tid;
      const int row = idx >> 3, c8 = (idx & 7) * 8;
      const int R = r0 + row, b = R >> 11, n = R & 2047;
      gl16(Oh + (((size_t)b * 16 + h) * 2048 + n) * 64 + c8,
           (char*)As + (size_t)(p * 256 + wbase) * 16);
    }
#pragma unroll
    for (int p = 0; p < 2; ++p) {  // B: wo rows d
      const int idx = p * 256 + tid;
      gl16(wo + (size_t)(c0 + (idx >> 3)) * 1024 + k0 + (idx & 7) * 8,
           (char*)Bs + (size_t)(p * 256 + wbase) * 16);
    }
    __syncthreads();
#pragma unroll
    for (int kf = 0; kf < 2; ++kf) {
      s16x8 a[4], b[2];
#pragma unroll
      for (int mi = 0; mi < 4; ++mi)
        a[mi] = *(const s16x8*)(&As[wr * 64 + mi * 16 + r][kf * 32 + g * 8]);
#pragma unroll
      for (int ni = 0; ni < 2; ++ni)
        b[ni] = *(const s16x8*)(&Bs[wc * 32 + ni * 16 + r][kf * 32 + g * 8]);
#pragma unroll
      for (int mi = 0; mi < 4; ++mi)
#pragma unroll
        for (int ni = 0; ni < 2; ++ni)
          acc[mi][ni] = __builtin_amdgcn_mfma_f32_16x16x32_bf16(a[mi], b[ni], acc[mi][ni], 0, 0, 0);
    }
  }
#pragma unroll
  for (int ni = 0; ni < 2; ++ni) {
    const int d = c0 + wc * 32 + ni * 16 + r;
#pragma unroll
    for (int mi = 0; mi < 4; ++mi) {
      const int rowb = r0 + wr * 64 + mi * 16 + g * 4;
#pragma unroll
      for (int i = 0; i < 4; ++i)
        out[(size_t)(rowb + i) * 1024 + d] = acc[mi][ni][i];
    }
  }
}

// ---------------------------------------------------------------------------
extern "C" void kernel_launch(void* const* d_in, const int* in_sizes, int n_in,
                              void* d_out, int out_size, void* d_ws, size_t ws_size,
                              hipStream_t stream) {
  (void)in_sizes; (void)n_in; (void)out_size; (void)ws_size;
  const float* x  = (const float*)d_in[0];
  const float* qp = (const float*)d_in[1];
  const float* kp = (const float*)d_in[2];
  const float* vp = (const float*)d_in[3];
  const float* op = (const float*)d_in[4];
  float* out = (float*)d_out;
  char* ws = (char*)d_ws;

  u16* xb = (u16*)(ws + OFF_XB);
  u16* Wb = (u16*)(ws + OFF_WB);
  u16* wo = (u16*)(ws + OFF_WO);
  u16* Qt = (u16*)(ws + OFF_QT);
  u16* Kh = (u16*)(ws + OFF_KH);
  u16* Vt = (u16*)(ws + OFF_VT);
  float* Zi = (float*)(ws + OFF_ZI);
  u16* Oh = (u16*)(ws + OFF_OH);

  k_cvt<<<3328, 256, 0, stream>>>(x, qp, kp, vp, op, xb, Wb, wo);
  k_qkv<<<dim3(24, 32), 256, 0, stream>>>(xb, Wb, Qt, Kh, Vt);
  k_colsum<<<dim3(32, 16, 2), 256, 0, stream>>>(Qt, Kh, Zi);
  k_attn<<<dim3(16, 16, 2), 512, 0, stream>>>(Qt, Kh, Vt, Zi, Oh);
  k_out<<<dim3(16, 32), 256, 0, stream>>>(Oh, wo, out);
}

// Round 14
// 117.291 us; speedup vs baseline: 1.1223x; 1.0206x over previous
//
#include <hip/hip_runtime.h>

// MultiHeadAttention (faithful-to-bug variant), round 13 = round 12 + ONE change:
// k_colsum v2 — Qt LDS staging removed; B-fragments loaded directly from global
// (perfectly coalesced 512B/wave segments, Qt L2-resident at 64KB/bh). All 32
// inner-loop barriers eliminated -> compiler free to software-pipeline. Per-lane
// accumulation order unchanged => Zi bit-identical. k_attn frozen (round-9 form);
// k_cvt / k_qkv / k_out byte-identical to round 12.
//   Qt[b,n,h,k] = sum_d x[b,n,d] * qp[k,h,d]   (mislabeled-einsum swap)
//   S = Qt·K^T per head ; softmax over n (axis=1 -> COLUMN softmax)
//   O = A·V ; out = O @ op

typedef float f32x4 __attribute__((ext_vector_type(4)));
typedef short s16x4 __attribute__((ext_vector_type(4)));
typedef short s16x8 __attribute__((ext_vector_type(8)));
typedef unsigned short u16;

namespace {
constexpr float C2 = 0.36067376022224085f;  // (1/sqrt(16)) * log2(e)

// workspace byte offsets (16B aligned); total footprint 33.25 MB
constexpr size_t OFF_XB = 0;                                  // xb [4096][1024] bf16
constexpr size_t OFF_WB = OFF_XB + (size_t)4096 * 1024 * 2;   // Wb [1536][1024] bf16
constexpr size_t OFF_WO = OFF_WB + (size_t)1536 * 1024 * 2;   // wo [1024][1024] bf16
constexpr size_t OFF_QT = OFF_WO + (size_t)1024 * 1024 * 2;   // Qt [2][16][2048][16] (pre-scaled)
constexpr size_t OFF_KH = OFF_QT + (size_t)2 * 16 * 2048 * 16 * 2;
constexpr size_t OFF_VT = OFF_KH + (size_t)2 * 16 * 2048 * 16 * 2;  // Vt [2][16][64][2048]
constexpr size_t OFF_ZI = OFF_VT + (size_t)2 * 16 * 64 * 2048 * 2;  // Zi [2][16][2048] f32
constexpr size_t OFF_OH = OFF_ZI + (size_t)2 * 16 * 2048 * 4;       // Oh [2][16][2048][64]
}  // namespace

__device__ __forceinline__ u16 f2bf(float f) {  // RNE f32->bf16
  union { float f; unsigned u; } v; v.f = f;
  return (u16)((v.u + 0x7FFF + ((v.u >> 16) & 1)) >> 16);
}
__device__ __forceinline__ unsigned cvtpk(float lo, float hi) {  // T12 recipe
  unsigned d;
  asm("v_cvt_pk_bf16_f32 %0, %1, %2" : "=v"(d) : "v"(lo), "v"(hi));
  return d;
}
__device__ __forceinline__ float fexp2(float x) {
#if __has_builtin(__builtin_amdgcn_exp2f)
  return __builtin_amdgcn_exp2f(x);
#else
  return exp2f(x);
#endif
}
__device__ __forceinline__ f32x4 mfma16(s16x4 a, s16x4 b, f32x4 c) {
#if __has_builtin(__builtin_amdgcn_mfma_f32_16x16x16_bf16)
  return __builtin_amdgcn_mfma_f32_16x16x16_bf16(a, b, c, 0, 0, 0);
#elif __has_builtin(__builtin_amdgcn_mfma_f32_16x16x16bf16_1k)
  return __builtin_amdgcn_mfma_f32_16x16x16bf16_1k(a, b, c, 0, 0, 0);
#else
  f32x4 d;
  asm volatile("v_mfma_f32_16x16x16_bf16 %0, %1, %2, %3"
               : "=v"(d) : "v"(a), "v"(b), "v"(c));
  return d;
#endif
}
__device__ __forceinline__ void gl16(const void* g, void* l) {  // 16B global->LDS
  __builtin_amdgcn_global_load_lds(
      (const __attribute__((address_space(1))) void*)g,
      (__attribute__((address_space(3))) void*)l, 16, 0, 0);
}

// ---------------------------------------------------------------------------
// k_cvt: f32 -> bf16; packs Wb rows [qp permuted | kp | vp], wo = op.
// ---------------------------------------------------------------------------
__global__ __launch_bounds__(256) void k_cvt(
    const float* __restrict__ x, const float* __restrict__ qp,
    const float* __restrict__ kp, const float* __restrict__ vp,
    const float* __restrict__ op, u16* __restrict__ xb,
    u16* __restrict__ Wb, u16* __restrict__ wo) {
  const int c = blockIdx.x * 256 + threadIdx.x;
  const int XC = (4096 * 1024) / 8, WC = (1536 * 1024) / 8, OC = (1024 * 1024) / 8;
  const float* src; u16* dst;
  if (c < XC) {
    src = x + (size_t)c * 8; dst = xb + (size_t)c * 8;
  } else if (c < XC + WC) {
    const int cc = c - XC;
    const int row = cc >> 7, col = cc & 127;
    if (row < 256) {
      const int h = row >> 4, k = row & 15;
      src = qp + (size_t)(k * 16 + h) * 1024 + col * 8;  // swapped einsum
    } else if (row < 512) {
      src = kp + (size_t)(row - 256) * 1024 + col * 8;
    } else {
      src = vp + (size_t)(row - 512) * 1024 + col * 8;
    }
    dst = Wb + (size_t)cc * 8;
  } else if (c < XC + WC + OC) {
    const int cc = c - XC - WC;
    src = op + (size_t)cc * 8; dst = wo + (size_t)cc * 8;
  } else {
    return;
  }
  float4 lo = *(const float4*)(src);
  float4 hi = *(const float4*)(src + 4);
  union { s16x8 v; unsigned w[4]; } o;
  o.w[0] = cvtpk(lo.x, lo.y); o.w[1] = cvtpk(lo.z, lo.w);
  o.w[2] = cvtpk(hi.x, hi.y); o.w[3] = cvtpk(hi.z, hi.w);
  *(s16x8*)dst = o.v;
}

// ---------------------------------------------------------------------------
// k_qkv: C[4096 x 1536] = xb @ Wb^T. 128x64 tile, BK=64, 4 waves (2x2),
// global_load_lds w16 into LINEAR LDS (m97 structure).
// Epilogue: Qt (scaled by C2) / Kh / Vt (transposed per head).
// ---------------------------------------------------------------------------
__global__ __launch_bounds__(256) void k_qkv(
    const u16* __restrict__ xb, const u16* __restrict__ Wb,
    u16* __restrict__ Qt, u16* __restrict__ Kh, u16* __restrict__ Vt) {
  __shared__ __align__(16) u16 As[128][64];
  __shared__ __align__(16) u16 Bs[64][64];
  const int tid = threadIdx.x;
  const int wave = tid >> 6, lane = tid & 63;
  const int g = lane >> 4, r = lane & 15;
  const int wr = wave >> 1, wc = wave & 1;
  const int r0 = blockIdx.y * 128, c0 = blockIdx.x * 64;
  const int wbase = tid & 192;

  f32x4 acc[4][2];
#pragma unroll
  for (int mi = 0; mi < 4; ++mi)
#pragma unroll
    for (int ni = 0; ni < 2; ++ni)
#pragma unroll
      for (int i = 0; i < 4; ++i) acc[mi][ni][i] = 0.f;

  for (int k0 = 0; k0 < 1024; k0 += 64) {
    __syncthreads();
#pragma unroll
    for (int p = 0; p < 4; ++p) {  // A: 128x64 = 1024 chunks
      const int idx = p * 256 + tid;
      gl16(xb + (size_t)(r0 + (idx >> 3)) * 1024 + k0 + (idx & 7) * 8,
           (char*)As + (size_t)(p * 256 + wbase) * 16);
    }
#pragma unroll
    for (int p = 0; p < 2; ++p) {  // B: 64x64 = 512 chunks
      const int idx = p * 256 + tid;
      gl16(Wb + (size_t)(c0 + (idx >> 3)) * 1024 + k0 + (idx & 7) * 8,
           (char*)Bs + (size_t)(p * 256 + wbase) * 16);
    }
    __syncthreads();
#pragma unroll
    for (int kf = 0; kf < 2; ++kf) {
      s16x8 a[4], b[2];
#pragma unroll
      for (int mi = 0; mi < 4; ++mi)
        a[mi] = *(const s16x8*)(&As[wr * 64 + mi * 16 + r][kf * 32 + g * 8]);
#pragma unroll
      for (int ni = 0; ni < 2; ++ni)
        b[ni] = *(const s16x8*)(&Bs[wc * 32 + ni * 16 + r][kf * 32 + g * 8]);
#pragma unroll
      for (int mi = 0; mi < 4; ++mi)
#pragma unroll
        for (int ni = 0; ni < 2; ++ni)
          acc[mi][ni] = __builtin_amdgcn_mfma_f32_16x16x32_bf16(a[mi], b[ni], acc[mi][ni], 0, 0, 0);
    }
  }
#pragma unroll
  for (int ni = 0; ni < 2; ++ni) {
    const int c = c0 + wc * 32 + ni * 16 + r;
#pragma unroll
    for (int mi = 0; mi < 4; ++mi) {
      const int rowb = r0 + wr * 64 + mi * 16 + g * 4;
      const int b = rowb >> 11, n = rowb & 2047;
      if (c < 256) {  // Qt, pre-scaled for exp2-direct softmax
        const int h = c >> 4, kk = c & 15;
        u16* p = Qt + (((size_t)b * 16 + h) * 2048 + n) * 16 + kk;
        p[0]  = f2bf(acc[mi][ni][0] * C2);
        p[16] = f2bf(acc[mi][ni][1] * C2);
        p[32] = f2bf(acc[mi][ni][2] * C2);
        p[48] = f2bf(acc[mi][ni][3] * C2);
      } else if (c < 512) {
        const int cc = c - 256;
        const int h = cc >> 4, kk = cc & 15;
        u16* p = Kh + (((size_t)b * 16 + h) * 2048 + n) * 16 + kk;
        p[0]  = f2bf(acc[mi][ni][0]);
        p[16] = f2bf(acc[mi][ni][1]);
        p[32] = f2bf(acc[mi][ni][2]);
        p[48] = f2bf(acc[mi][ni][3]);
      } else {
        const int cc = c - 512;
        const int h = cc >> 6, v = cc & 63;
        ushort4 o;
        o.x = f2bf(acc[mi][ni][0]); o.y = f2bf(acc[mi][ni][1]);
        o.z = f2bf(acc[mi][ni][2]); o.w = f2bf(acc[mi][ni][3]);
        *(ushort4*)(Vt + (((size_t)b * 16 + h) * 64 + v) * 2048 + n) = o;
      }
    }
  }
}

// ---------------------------------------------------------------------------
// k_colsum v2: Zi[b,h,m] = 1 / sum_n exp2(S'[n,m])  (Qt pre-scaled by C2).
// Qt B-fragments loaded DIRECTLY from global (coalesced 512B/wave segments,
// L2-resident); no inner-loop barriers or LDS staging. Same per-lane
// accumulation order as v1 => bit-identical Zi.
// ---------------------------------------------------------------------------
__global__ __launch_bounds__(256) void k_colsum(
    const u16* __restrict__ Qt, const u16* __restrict__ Kh,
    float* __restrict__ Zi) {
  const int m0 = blockIdx.x * 64;
  const int bh = blockIdx.z * 16 + blockIdx.y;
  const u16* qbase = Qt + (size_t)bh * 2048 * 16;
  const u16* kbase = Kh + (size_t)bh * 2048 * 16;
  __shared__ __align__(16) u16 Ks[64][20];
  __shared__ float Zp[4][64];
  const int tid = threadIdx.x;
  const int wave = tid >> 6, lane = tid & 63;
  const int g = lane >> 4, r = lane & 15;

  {  // stage K tile once
    const int row = tid >> 2, c4 = (tid & 3) * 4;
    *(s16x4*)(&Ks[row][c4]) = *(const s16x4*)(kbase + (size_t)(m0 + row) * 16 + c4);
  }
  __syncthreads();
  s16x4 afr[4];
#pragma unroll
  for (int mf = 0; mf < 4; ++mf) afr[mf] = *(const s16x4*)(&Ks[mf * 16 + r][g * 4]);

  float z[4][4];
#pragma unroll
  for (int mf = 0; mf < 4; ++mf)
#pragma unroll
    for (int i = 0; i < 4; ++i) z[mf][i] = 0.f;

  for (int n0 = 0; n0 < 2048; n0 += 128) {
#pragma unroll
    for (int nf = 0; nf < 2; ++nf) {
      const s16x4 bfr = *(const s16x4*)(
          qbase + (size_t)(n0 + wave * 32 + nf * 16 + r) * 16 + g * 4);
#pragma unroll
      for (int mf = 0; mf < 4; ++mf) {
        f32x4 st; st[0] = 0.f; st[1] = 0.f; st[2] = 0.f; st[3] = 0.f;
        st = mfma16(afr[mf], bfr, st);
#pragma unroll
        for (int i = 0; i < 4; ++i) z[mf][i] += fexp2(st[i]);
      }
    }
  }
#pragma unroll
  for (int mf = 0; mf < 4; ++mf)
#pragma unroll
    for (int i = 0; i < 4; ++i) {
      float v = z[mf][i];
      v += __shfl_xor(v, 1); v += __shfl_xor(v, 2);
      v += __shfl_xor(v, 4); v += __shfl_xor(v, 8);
      z[mf][i] = v;
    }
  if (r == 0) {
#pragma unroll
    for (int mf = 0; mf < 4; ++mf)
#pragma unroll
      for (int i = 0; i < 4; ++i) Zp[wave][mf * 16 + g * 4 + i] = z[mf][i];
  }
  __syncthreads();
  if (tid < 64) {
    Zi[(size_t)bh * 2048 + m0 + tid] =
        1.0f / (Zp[0][tid] + Zp[1][tid] + Zp[2][tid] + Zp[3][tid]);
  }
}

// ---------------------------------------------------------------------------
// k_attn: round-9 validated form (BYTE-IDENTICAL, frozen). 8 waves / 512
// threads; waves 0-3 sweep m in [0,1024), waves 4-7 [1024,2048); partial O^T
// combined via comb (union-overlaid on Ks/Vs/Zs). P = exp2(S')*Zi[m] bf16.
// ---------------------------------------------------------------------------
__global__ __launch_bounds__(512) void k_attn(
    const u16* __restrict__ Qt, const u16* __restrict__ Kh,
    const u16* __restrict__ Vt, const float* __restrict__ Zi,
    u16* __restrict__ Oh) {
  const int n0 = blockIdx.x * 128;
  const int bh = blockIdx.z * 16 + blockIdx.y;
  const u16* qbase = Qt + (size_t)bh * 2048 * 16;
  const u16* kbase = Kh + (size_t)bh * 2048 * 16;
  const u16* vbase = Vt + (size_t)bh * 64 * 2048;
  const float* zbase = Zi + (size_t)bh * 2048;
  u16* obase = Oh + (size_t)bh * 2048 * 64;

  __shared__ __align__(16) union ShMem {
    struct { u16 Ks[2][64][20]; u16 Vs[2][64][72]; float Zs[2][64]; } s;
    float comb[4][32][68];
  } u;

  const int tid = threadIdx.x;
  const int wave = tid >> 6, lane = tid & 63;
  const int g = lane >> 4, r = lane & 15;
  const int half = wave >> 2, wq = wave & 3;

  s16x4 qfr[2];
#pragma unroll
  for (int nf = 0; nf < 2; ++nf)
    qfr[nf] = *(const s16x4*)(qbase + (size_t)(n0 + wq * 32 + nf * 16 + r) * 16 + g * 4);

  f32x4 oacc[4][2];
#pragma unroll
  for (int vf = 0; vf < 4; ++vf)
#pragma unroll
    for (int nf = 0; nf < 2; ++nf)
#pragma unroll
      for (int i = 0; i < 4; ++i) oacc[vf][nf][i] = 0.f;

  const int ks_hk = tid >> 8, ks_rem = tid & 255;
  const int ks_row = ks_rem >> 2, ks_c4 = (ks_rem & 3) * 4;

  for (int t = 0; t < 16; ++t) {
    __syncthreads();
    // stage K tiles for both halves: 2 x 64 x 16 = 512 s16x4 chunks
    *(s16x4*)(&u.s.Ks[ks_hk][ks_row][ks_c4]) =
        *(const s16x4*)(kbase + (size_t)(ks_hk * 1024 + t * 64 + ks_row) * 16 + ks_c4);
    // stage V tiles for both halves: 2 x 64 x 64 = 1024 s16x8 chunks
#pragma unroll
    for (int p = 0; p < 2; ++p) {
      const int q = p * 512 + tid;
      const int hv = q >> 9, rem = q & 511;
      const int v = rem >> 3, c8 = (rem & 7) * 8;
      *(s16x8*)(&u.s.Vs[hv][v][c8]) =
          *(const s16x8*)(vbase + (size_t)v * 2048 + hv * 1024 + t * 64 + c8);
    }
    // stage Zi for both halves' m-tiles
    if (tid < 128) u.s.Zs[tid >> 6][tid & 63] = zbase[(tid >> 6) * 1024 + t * 64 + (tid & 63)];
    __syncthreads();

    s16x4 kfr[4], va[4][4];
#pragma unroll
    for (int mf = 0; mf < 4; ++mf)
      kfr[mf] = *(const s16x4*)(&u.s.Ks[half][mf * 16 + r][g * 4]);
#pragma unroll
    for (int vf = 0; vf < 4; ++vf)
#pragma unroll
      for (int mf = 0; mf < 4; ++mf)
        va[vf][mf] = *(const s16x4*)(&u.s.Vs[half][vf * 16 + r][mf * 16 + g * 4]);

#pragma unroll
    for (int nf = 0; nf < 2; ++nf) {
      s16x4 pb[4];
#pragma unroll
      for (int mf = 0; mf < 4; ++mf) {
        f32x4 st; st[0] = 0.f; st[1] = 0.f; st[2] = 0.f; st[3] = 0.f;
        st = mfma16(kfr[mf], qfr[nf], st);
        union { s16x4 v4; unsigned w[2]; } pk;
        const int mloc = mf * 16 + g * 4;
        pk.w[0] = cvtpk(fexp2(st[0]) * u.s.Zs[half][mloc + 0],
                        fexp2(st[1]) * u.s.Zs[half][mloc + 1]);
        pk.w[1] = cvtpk(fexp2(st[2]) * u.s.Zs[half][mloc + 2],
                        fexp2(st[3]) * u.s.Zs[half][mloc + 3]);
        pb[mf] = pk.v4;
      }
#pragma unroll
      for (int vf = 0; vf < 4; ++vf)
#pragma unroll
        for (int mf = 0; mf < 4; ++mf)
          oacc[vf][nf] = mfma16(va[vf][mf], pb[mf], oacc[vf][nf]);
    }
  }

  __syncthreads();  // all Ks/Vs/Zs reads done; comb may now overwrite them
  if (half == 1) {
#pragma unroll
    for (int nf = 0; nf < 2; ++nf)
#pragma unroll
      for (int vf = 0; vf < 4; ++vf)
#pragma unroll
        for (int i = 0; i < 4; ++i)
          u.comb[wq][nf * 16 + r][vf * 16 + g * 4 + i] = oacc[vf][nf][i];
  }
  __syncthreads();
  if (half == 0) {
#pragma unroll
    for (int nf = 0; nf < 2; ++nf)
#pragma unroll
      for (int vf = 0; vf < 4; ++vf)
#pragma unroll
        for (int i = 0; i < 4; ++i)
          oacc[vf][nf][i] += u.comb[wq][nf * 16 + r][vf * 16 + g * 4 + i];
#pragma unroll
    for (int nf = 0; nf < 2; ++nf) {
      const int n = n0 + wq * 32 + nf * 16 + r;
#pragma unroll
      for (int vf = 0; vf < 4; ++vf) {
        union { s16x4 v4; unsigned w[2]; } pk;
        pk.w[0] = cvtpk(oacc[vf][nf][0], oacc[vf][nf][1]);
        pk.w[1] = cvtpk(oacc[vf][nf][2], oacc[vf][nf][3]);
        *(s16x4*)(obase + (size_t)n * 64 + vf * 16 + g * 4) = pk.v4;
      }
    }
  }
}

// ---------------------------------------------------------------------------
// k_out: out[4096 x 1024] = Oh(bn x hv) @ wo^T, f32 out. m97-style staging.
// ---------------------------------------------------------------------------
__global__ __launch_bounds__(256) void k_out(
    const u16* __restrict__ Oh, const u16* __restrict__ wo,
    float* __restrict__ out) {
  __shared__ __align__(16) u16 As[128][64];
  __shared__ __align__(16) u16 Bs[64][64];
  const int tid = threadIdx.x;
  const int wave = tid >> 6, lane = tid & 63;
  const int g = lane >> 4, r = lane & 15;
  const int wr = wave >> 1, wc = wave & 1;
  const int r0 = blockIdx.y * 128, c0 = blockIdx.x * 64;
  const int wbase = tid & 192;

  f32x4 acc[4][2];
#pragma unroll
  for (int mi = 0; mi < 4; ++mi)
#pragma unroll
    for (int ni = 0; ni < 2; ++ni)
#pragma unroll
      for (int i = 0; i < 4; ++i) acc[mi][ni][i] = 0.f;

  for (int k0 = 0; k0 < 1024; k0 += 64) {
    const int h = k0 >> 6;
    __syncthreads();
#pragma unroll
    for (int p = 0; p < 4; ++p) {  // A: Oh rows (b,n), k-slice = head h
      const int idx = p * 256 + tid;
      const int row = idx >> 3, c8 = (idx & 7) * 8;
      const int R = r0 + row, b = R >> 11, n = R & 2047;
      gl16(Oh + (((size_t)b * 16 + h) * 2048 + n) * 64 + c8,
           (char*)As + (size_t)(p * 256 + wbase) * 16);
    }
#pragma unroll
    for (int p = 0; p < 2; ++p) {  // B: wo rows d
      const int idx = p * 256 + tid;
      gl16(wo + (size_t)(c0 + (idx >> 3)) * 1024 + k0 + (idx & 7) * 8,
           (char*)Bs + (size_t)(p * 256 + wbase) * 16);
    }
    __syncthreads();
#pragma unroll
    for (int kf = 0; kf < 2; ++kf) {
      s16x8 a[4], b[2];
#pragma unroll
      for (int mi = 0; mi < 4; ++mi)
        a[mi] = *(const s16x8*)(&As[wr * 64 + mi * 16 + r][kf * 32 + g * 8]);
#pragma unroll
      for (int ni = 0; ni < 2; ++ni)
        b[ni] = *(const s16x8*)(&Bs[wc * 32 + ni * 16 + r][kf * 32 + g * 8]);
#pragma unroll
      for (int mi = 0; mi < 4; ++mi)
#pragma unroll
        for (int ni = 0; ni < 2; ++ni)
          acc[mi][ni] = __builtin_amdgcn_mfma_f32_16x16x32_bf16(a[mi], b[ni], acc[mi][ni], 0, 0, 0);
    }
  }
#pragma unroll
  for (int ni = 0; ni < 2; ++ni) {
    const int d = c0 + wc * 32 + ni * 16 + r;
#pragma unroll
    for (int mi = 0; mi < 4; ++mi) {
      const int rowb = r0 + wr * 64 + mi * 16 + g * 4;
#pragma unroll
      for (int i = 0; i < 4; ++i)
        out[(size_t)(rowb + i) * 1024 + d] = acc[mi][ni][i];
    }
  }
}

// ---------------------------------------------------------------------------
extern "C" void kernel_launch(void* const* d_in, const int* in_sizes, int n_in,
                              void* d_out, int out_size, void* d_ws, size_t ws_size,
                              hipStream_t stream) {
  (void)in_sizes; (void)n_in; (void)out_size; (void)ws_size;
  const float* x  = (const float*)d_in[0];
  const float* qp = (const float*)d_in[1];
  const float* kp = (const float*)d_in[2];
  const float* vp = (const float*)d_in[3];
  const float* op = (const float*)d_in[4];
  float* out = (float*)d_out;
  char* ws = (char*)d_ws;

  u16* xb = (u16*)(ws + OFF_XB);
  u16* Wb = (u16*)(ws + OFF_WB);
  u16* wo = (u16*)(ws + OFF_WO);
  u16* Qt = (u16*)(ws + OFF_QT);
  u16* Kh = (u16*)(ws + OFF_KH);
  u16* Vt = (u16*)(ws + OFF_VT);
  float* Zi = (float*)(ws + OFF_ZI);
  u16* Oh = (u16*)(ws + OFF_OH);

  k_cvt<<<3328, 256, 0, stream>>>(x, qp, kp, vp, op, xb, Wb, wo);
  k_qkv<<<dim3(24, 32), 256, 0, stream>>>(xb, Wb, Qt, Kh, Vt);
  k_colsum<<<dim3(32, 16, 2), 256, 0, stream>>>(Qt, Kh, Zi);
  k_attn<<<dim3(16, 16, 2), 512, 0, stream>>>(Qt, Kh, Vt, Zi, Oh);
  k_out<<<dim3(16, 32), 256, 0, stream>>>(Oh, wo, out);
}